// Round 1
// baseline (117.502 us; speedup 1.0000x reference)
//
#include <hip/hip_runtime.h>
#include <cstddef>
#include <cstdint>

constexpr int BATCH   = 4096;
constexpr int IN_DIM  = 8192;
constexpr int OUT_DIM = 16384;
constexpr int THREADS = 512;           // threads per block (8 waves)
constexpr int RPB     = 2;             // batch rows per block (64 KB LDS)
constexpr int OPT     = 4;             // outputs per thread per iteration
constexpr int ITERS   = OUT_DIM / (THREADS * OPT);  // 8

// softmax over 16 gate logits collapsed to (c0, ca, cb, cab)
__device__ __forceinline__ float4 softmax_coef(const float* __restrict__ wrow) {
  const float4* wp = reinterpret_cast<const float4*>(wrow);
  float4 t0 = wp[0], t1 = wp[1], t2 = wp[2], t3 = wp[3];
  float w[16] = { t0.x, t0.y, t0.z, t0.w,
                  t1.x, t1.y, t1.z, t1.w,
                  t2.x, t2.y, t2.z, t2.w,
                  t3.x, t3.y, t3.z, t3.w };
  float m = w[0];
#pragma unroll
  for (int i = 1; i < 16; ++i) m = fmaxf(m, w[i]);
  float p[16];
  float s = 0.f;
#pragma unroll
  for (int i = 0; i < 16; ++i) { p[i] = __expf(w[i] - m); s += p[i]; }
  const float inv = 1.0f / s;
  // gate coefficient table rows: (const), (a), (b), (ab)
  const float GC[16]  = {0,0,0,0, 0,0,0,0, 1,1,1,1, 1,1,1,1};
  const float GA[16]  = {0,0,1,1, 0,0,1,1, -1,-1,0,0, -1,-1,0,0};
  const float GB[16]  = {0,0,0,0, 1,1,1,1, -1,-1,-1,-1, 0,0,0,0};
  const float GAB[16] = {0,1,-1,0, -1,0,-2,-1, 1,2,0,1, 0,1,-1,0};
  float c0 = 0.f, ca = 0.f, cb = 0.f, cab = 0.f;
#pragma unroll
  for (int i = 0; i < 16; ++i) {
    c0  += p[i] * GC[i];
    ca  += p[i] * GA[i];
    cb  += p[i] * GB[i];
    cab += p[i] * GAB[i];
  }
  return make_float4(c0 * inv, ca * inv, cb * inv, cab * inv);
}

__global__ __launch_bounds__(256)
void coef_kernel(const float* __restrict__ weights, float4* __restrict__ coef) {
  const int o = blockIdx.x * 256 + threadIdx.x;
  if (o < OUT_DIM) coef[o] = softmax_coef(weights + (size_t)o * 16);
}

template <bool USE_WS>
__global__ __launch_bounds__(THREADS)
void logic_main(const float* __restrict__ x,
                const float4* __restrict__ coef,
                const float* __restrict__ weights,
                const int* __restrict__ idx_a,
                const int* __restrict__ idx_b,
                float* __restrict__ out) {
  __shared__ float rows[RPB][IN_DIM];           // 64 KB: 2 batch rows of x

  const int b0 = blockIdx.x * RPB;

  // Stage RPB contiguous rows of x into LDS with coalesced float4 copies.
  {
    const float4* __restrict__ src =
        reinterpret_cast<const float4*>(x + (size_t)b0 * IN_DIM);
    float4* __restrict__ dst = reinterpret_cast<float4*>(&rows[0][0]);
    constexpr int V4 = RPB * IN_DIM / 4;        // 4096 float4
#pragma unroll
    for (int i = threadIdx.x; i < V4; i += THREADS) dst[i] = src[i];
  }
  __syncthreads();

#pragma unroll
  for (int it = 0; it < ITERS; ++it) {
    const int o = (it * THREADS + threadIdx.x) * OPT;

    const int4 ia = *reinterpret_cast<const int4*>(idx_a + o);
    const int4 ib = *reinterpret_cast<const int4*>(idx_b + o);

    float4 c0, c1, c2, c3;
    if (USE_WS) {
      c0 = coef[o + 0]; c1 = coef[o + 1]; c2 = coef[o + 2]; c3 = coef[o + 3];
    } else {
      c0 = softmax_coef(weights + (size_t)(o + 0) * 16);
      c1 = softmax_coef(weights + (size_t)(o + 1) * 16);
      c2 = softmax_coef(weights + (size_t)(o + 2) * 16);
      c3 = softmax_coef(weights + (size_t)(o + 3) * 16);
    }

#pragma unroll
    for (int r = 0; r < RPB; ++r) {
      const float* __restrict__ row = rows[r];
      const float a0 = row[ia.x], a1 = row[ia.y], a2 = row[ia.z], a3 = row[ia.w];
      const float v0 = row[ib.x], v1 = row[ib.y], v2 = row[ib.z], v3 = row[ib.w];
      float4 res;
      res.x = fmaf(fmaf(c0.w, a0, c0.z), v0, fmaf(c0.y, a0, c0.x));
      res.y = fmaf(fmaf(c1.w, a1, c1.z), v1, fmaf(c1.y, a1, c1.x));
      res.z = fmaf(fmaf(c2.w, a2, c2.z), v2, fmaf(c2.y, a2, c2.x));
      res.w = fmaf(fmaf(c3.w, a3, c3.z), v3, fmaf(c3.y, a3, c3.x));
      *reinterpret_cast<float4*>(out + (size_t)(b0 + r) * OUT_DIM + o) = res;
    }
  }
}

extern "C" void kernel_launch(void* const* d_in, const int* in_sizes, int n_in,
                              void* d_out, int out_size, void* d_ws, size_t ws_size,
                              hipStream_t stream) {
  const float* x       = (const float*)d_in[0];
  const float* weights = (const float*)d_in[1];
  const int*   idx_a   = (const int*)d_in[2];
  const int*   idx_b   = (const int*)d_in[3];
  float*       out     = (float*)d_out;

  const size_t coef_bytes = (size_t)OUT_DIM * 4 * sizeof(float);  // 256 KB
  const bool use_ws = (d_ws != nullptr) && (ws_size >= coef_bytes);

  if (use_ws) {
    float4* coef = (float4*)d_ws;
    coef_kernel<<<OUT_DIM / 256, 256, 0, stream>>>(weights, coef);
    logic_main<true><<<BATCH / RPB, THREADS, 0, stream>>>(
        x, coef, weights, idx_a, idx_b, out);
  } else {
    logic_main<false><<<BATCH / RPB, THREADS, 0, stream>>>(
        x, nullptr, weights, idx_a, idx_b, out);
  }
}

// Round 3
// 108.874 us; speedup vs baseline: 1.0792x; 1.0792x over previous
//
#include <hip/hip_runtime.h>
#include <cstddef>
#include <cstdint>

constexpr int BATCH   = 4096;
constexpr int IN_DIM  = 8192;
constexpr int OUT_DIM = 16384;
constexpr int THREADS = 512;           // 8 waves per block
constexpr int RPB     = 2;             // batch rows per block, pair-interleaved in LDS
constexpr int OPT     = 4;             // outputs per thread per iteration
constexpr int ITERS   = OUT_DIM / (THREADS * OPT);        // 8
constexpr int SSTEPS  = IN_DIM / (THREADS * 2);           // 8 staging steps

// clang-native vector types (accepted by __builtin_nontemporal_*)
typedef float f32x2 __attribute__((ext_vector_type(2)));
typedef float f32x4 __attribute__((ext_vector_type(4)));

// softmax over 16 gate logits collapsed to (c0, ca, cb, cab)
__device__ __forceinline__ float4 softmax_coef(const float* __restrict__ wrow) {
  const float4* wp = reinterpret_cast<const float4*>(wrow);
  float4 t0 = wp[0], t1 = wp[1], t2 = wp[2], t3 = wp[3];
  float w[16] = { t0.x, t0.y, t0.z, t0.w,
                  t1.x, t1.y, t1.z, t1.w,
                  t2.x, t2.y, t2.z, t2.w,
                  t3.x, t3.y, t3.z, t3.w };
  float m = w[0];
#pragma unroll
  for (int i = 1; i < 16; ++i) m = fmaxf(m, w[i]);
  float p[16];
  float s = 0.f;
#pragma unroll
  for (int i = 0; i < 16; ++i) { p[i] = __expf(w[i] - m); s += p[i]; }
  const float inv = 1.0f / s;
  const float GC[16]  = {0,0,0,0, 0,0,0,0, 1,1,1,1, 1,1,1,1};
  const float GA[16]  = {0,0,1,1, 0,0,1,1, -1,-1,0,0, -1,-1,0,0};
  const float GB[16]  = {0,0,0,0, 1,1,1,1, -1,-1,-1,-1, 0,0,0,0};
  const float GAB[16] = {0,1,-1,0, -1,0,-2,-1, 1,2,0,1, 0,1,-1,0};
  float c0 = 0.f, ca = 0.f, cb = 0.f, cab = 0.f;
#pragma unroll
  for (int i = 0; i < 16; ++i) {
    c0  += p[i] * GC[i];
    ca  += p[i] * GA[i];
    cb  += p[i] * GB[i];
    cab += p[i] * GAB[i];
  }
  return make_float4(c0 * inv, ca * inv, cb * inv, cab * inv);
}

__global__ __launch_bounds__(256)
void coef_kernel(const float* __restrict__ weights, float4* __restrict__ coef) {
  const int o = blockIdx.x * 256 + threadIdx.x;
  if (o < OUT_DIM) coef[o] = softmax_coef(weights + (size_t)o * 16);
}

__global__ __launch_bounds__(THREADS)
void logic_main(const float* __restrict__ x,
                const float4* __restrict__ coef,
                const int* __restrict__ idx_a,
                const int* __restrict__ idx_b,
                float* __restrict__ out) {
  // pair-interleaved x: xpair[i] = { x[b0][2i], x[b1][2i], x[b0][2i+1], x[b1][2i+1] }
  __shared__ float4 xpair[IN_DIM / 2];                     // 64 KB
  const float2* __restrict__ pr = reinterpret_cast<const float2*>(xpair);

  const int t  = threadIdx.x;
  const int b0 = blockIdx.x * RPB;

  const f32x2* __restrict__ r0 =
      reinterpret_cast<const f32x2*>(x + (size_t)b0 * IN_DIM);
  const f32x2* __restrict__ r1 =
      reinterpret_cast<const f32x2*>(x + (size_t)(b0 + 1) * IN_DIM);

  // ---- prefetch iteration-0 idx/coef (hides L2 latency under staging) ----
  int o0 = t * OPT;
  int4   ia = *reinterpret_cast<const int4*>(idx_a + o0);
  int4   ib = *reinterpret_cast<const int4*>(idx_b + o0);
  float4 c0 = coef[o0 + 0], c1 = coef[o0 + 1],
         c2 = coef[o0 + 2], c3 = coef[o0 + 3];

  // ---- stage 2 rows, pair-interleaved; NT loads (x has zero reuse) ----
#pragma unroll
  for (int s = 0; s < SSTEPS; ++s) {
    const int p = s * THREADS + t;                         // float2-pair index
    f32x2 a = __builtin_nontemporal_load(r0 + p);
    f32x2 b = __builtin_nontemporal_load(r1 + p);
    xpair[p] = make_float4(a.x, b.x, a.y, b.y);            // ds_write_b128, bank-rotating
  }
  __syncthreads();

#pragma unroll
  for (int it = 0; it < ITERS; ++it) {
    const int o = it * THREADS * OPT + t * OPT;

    // prefetch next iteration's streams
    int4 ia_n, ib_n;
    float4 cn0, cn1, cn2, cn3;
    if (it + 1 < ITERS) {
      const int on = o + THREADS * OPT;
      ia_n = *reinterpret_cast<const int4*>(idx_a + on);
      ib_n = *reinterpret_cast<const int4*>(idx_b + on);
      cn0 = coef[on + 0]; cn1 = coef[on + 1];
      cn2 = coef[on + 2]; cn3 = coef[on + 3];
    }

    // one ds_read_b64 per operand serves BOTH rows
    const float2 A0 = pr[ia.x], A1 = pr[ia.y], A2 = pr[ia.z], A3 = pr[ia.w];
    const float2 B0 = pr[ib.x], B1 = pr[ib.y], B2 = pr[ib.z], B3 = pr[ib.w];

    f32x4 res0, res1;
    res0.x = fmaf(fmaf(c0.w, A0.x, c0.z), B0.x, fmaf(c0.y, A0.x, c0.x));
    res1.x = fmaf(fmaf(c0.w, A0.y, c0.z), B0.y, fmaf(c0.y, A0.y, c0.x));
    res0.y = fmaf(fmaf(c1.w, A1.x, c1.z), B1.x, fmaf(c1.y, A1.x, c1.x));
    res1.y = fmaf(fmaf(c1.w, A1.y, c1.z), B1.y, fmaf(c1.y, A1.y, c1.x));
    res0.z = fmaf(fmaf(c2.w, A2.x, c2.z), B2.x, fmaf(c2.y, A2.x, c2.x));
    res1.z = fmaf(fmaf(c2.w, A2.y, c2.z), B2.y, fmaf(c2.y, A2.y, c2.x));
    res0.w = fmaf(fmaf(c3.w, A3.x, c3.z), B3.x, fmaf(c3.y, A3.x, c3.x));
    res1.w = fmaf(fmaf(c3.w, A3.y, c3.z), B3.y, fmaf(c3.y, A3.y, c3.x));

    __builtin_nontemporal_store(
        res0, reinterpret_cast<f32x4*>(out + (size_t)b0 * OUT_DIM + o));
    __builtin_nontemporal_store(
        res1, reinterpret_cast<f32x4*>(out + (size_t)(b0 + 1) * OUT_DIM + o));

    ia = ia_n; ib = ib_n;
    c0 = cn0; c1 = cn1; c2 = cn2; c3 = cn3;
  }
}

extern "C" void kernel_launch(void* const* d_in, const int* in_sizes, int n_in,
                              void* d_out, int out_size, void* d_ws, size_t ws_size,
                              hipStream_t stream) {
  const float* x       = (const float*)d_in[0];
  const float* weights = (const float*)d_in[1];
  const int*   idx_a   = (const int*)d_in[2];
  const int*   idx_b   = (const int*)d_in[3];
  float*       out     = (float*)d_out;

  float4* coef = (float4*)d_ws;   // 256 KB needed; ws is at least out-sized
  coef_kernel<<<OUT_DIM / 256, 256, 0, stream>>>(weights, coef);
  logic_main<<<BATCH / RPB, THREADS, 0, stream>>>(x, coef, idx_a, idx_b, out);
}